// Round 12
// baseline (24406.418 us; speedup 1.0000x reference)
//
#include <hip/hip_runtime.h>
#include <hip/hip_bf16.h>

// MultilayerGRU: B=128, S=512, H=1024, L=2, O=1024
// Round 12: batch-split independent chains (4 groups x 64 WGs).
//  - L0-a (rows 0-63), L0-b (rows 64-127): self-contained 2-phase chains
//  - L1-a, L1-b: zr phase + g/OUT phase; Wh1/Why in LDS, Wx1 from L2 (bf16 copy)
//  - all exchange mechanisms identical to round 8 (write-once seqs, sc0sc1
//    stores, packed-flag relaxed polls); no census / relay / L2-invalidate

typedef __bf16 bf16;
typedef __attribute__((ext_vector_type(8))) __bf16 bf16x8;
typedef __attribute__((ext_vector_type(4))) __bf16 bf16x4;
typedef __attribute__((ext_vector_type(4))) float f32x4;

#define MFMA16(a, b, c) __builtin_amdgcn_mfma_f32_16x16x32_bf16(a, b, c, 0, 0, 0)

static __device__ __forceinline__ bf16x8 ldfrag(const bf16* p) {
  return *reinterpret_cast<const bf16x8*>(p);
}
static __device__ __forceinline__ float sigmf(float x) { return 1.f / (1.f + __expf(-x)); }

static __device__ __forceinline__ void st2_llc(bf16* p, bf16 v) {
  unsigned u = (unsigned)__builtin_bit_cast(unsigned short, v);
  asm volatile("global_store_short %0, %1, off sc0 sc1" :: "v"(p), "v"(u) : "memory");
}
static __device__ __forceinline__ bf16x8 ldA_sc(const bf16* p) {
  union { unsigned long long q[2]; bf16x8 v; } u;
  u.q[0] = __hip_atomic_load((const unsigned long long*)p, __ATOMIC_RELAXED,
                             __HIP_MEMORY_SCOPE_AGENT);
  u.q[1] = __hip_atomic_load(((const unsigned long long*)p) + 1, __ATOMIC_RELAXED,
                             __HIP_MEMORY_SCOPE_AGENT);
  return u.v;
}
static __device__ __forceinline__ void spin1(const int* p, int want) {
  while (__hip_atomic_load(p, __ATOMIC_RELAXED, __HIP_MEMORY_SCOPE_AGENT) < want)
    __builtin_amdgcn_s_sleep(1);
}
static __device__ __forceinline__ void publish(int* p, int val) {
  asm volatile("s_waitcnt vmcnt(0)" ::: "memory");
  __syncthreads();
  if (threadIdx.x == 0)
    __hip_atomic_store(p, val, __ATOMIC_RELAXED, __HIP_MEMORY_SCOPE_AGENT);
}

// ---------------- weight cast (all Wx -> bf16; layer0 for gx0, layer1 for L1) --
__global__ void k_cast4(const float* __restrict__ s, bf16* __restrict__ d, int n4) {
  int i = blockIdx.x * blockDim.x + threadIdx.x;
  int st = gridDim.x * blockDim.x;
  for (; i < n4; i += st) {
    float4 v = reinterpret_cast<const float4*>(s)[i];
    bf16x4 o = {(bf16)v.x, (bf16)v.y, (bf16)v.z, (bf16)v.w};
    *reinterpret_cast<bf16x4*>(d + (size_t)i * 4) = o;
  }
}

// ---------------- gx0T[s][col][b] = (x @ Wx0^T + bh0) transposed ----------------
__global__ __launch_bounds__(256) void k_gx0T(const float* __restrict__ x,
                                              const bf16* __restrict__ wx0,
                                              const float* __restrict__ bh,
                                              bf16* __restrict__ gx0T) {
  const int lane = threadIdx.x & 63;
  const int gw = blockIdx.x * 4 + (threadIdx.x >> 6);
  const int NT = 3072 / 64;
  const int tm = gw / NT, tn = gw % NT;
  const int m0 = tm * 64, n0 = tn * 64;
  const int r = lane & 15, kq = lane >> 4;
  f32x4 acc[4][4] = {};
  for (int k0 = 0; k0 < 1024; k0 += 32) {
    const int k = k0 + kq * 8;
    bf16x8 a[4], b[4];
#pragma unroll
    for (int mi = 0; mi < 4; ++mi) {
      const int m = m0 + mi * 16 + r;
      const int bb = m & 127, s = m >> 7;
      const float* xp = x + ((size_t)(bb * 512 + s)) * 1024 + k;
      float4 lo = *reinterpret_cast<const float4*>(xp);
      float4 hi = *reinterpret_cast<const float4*>(xp + 4);
      bf16x8 av;
      av[0] = (bf16)lo.x; av[1] = (bf16)lo.y; av[2] = (bf16)lo.z; av[3] = (bf16)lo.w;
      av[4] = (bf16)hi.x; av[5] = (bf16)hi.y; av[6] = (bf16)hi.z; av[7] = (bf16)hi.w;
      a[mi] = av;
    }
#pragma unroll
    for (int ni = 0; ni < 4; ++ni)
      b[ni] = ldfrag(wx0 + (size_t)(n0 + ni * 16 + r) * 1024 + k);
#pragma unroll
    for (int mi = 0; mi < 4; ++mi)
#pragma unroll
      for (int ni = 0; ni < 4; ++ni) acc[mi][ni] = MFMA16(a[mi], b[ni], acc[mi][ni]);
  }
#pragma unroll
  for (int mi = 0; mi < 4; ++mi) {
#pragma unroll
    for (int ni = 0; ni < 4; ++ni) {
      const int col = n0 + ni * 16 + r;
      const float bias = bh[col];
      bf16x4 v;
#pragma unroll
      for (int j = 0; j < 4; ++j) v[j] = (bf16)(acc[mi][ni][j] + bias);
      const int m = m0 + mi * 16 + kq * 4;
      const int s = m >> 7, bb = m & 127;
      *reinterpret_cast<bf16x4*>(gx0T + ((size_t)s * 3072 + col) * 128 + bb) = v;
    }
  }
}

// ---------------- persistent GRU scan ----------------
struct GP {
  const float* Wh;
  const float* bh;
  const float* by;
  const float* Why;
  const bf16* Wxb;   // [2][3][1024][1024] bf16
  const bf16* gx0T;
  bf16* h0seq;       // 513 x [128][1024] write-once
  bf16* h1seq;       // 513 x write-once
  bf16* rh0;         // 512 x or 2 x parity
  bf16* rh1;
  float* out;
  int* bar;
  int sc_rh;
};

__device__ __forceinline__ void stage_row8(char* dst, int row, int rb, int k8,
                                           const float* __restrict__ src) {
  const float4 f0 = *reinterpret_cast<const float4*>(src);
  const float4 f1 = *reinterpret_cast<const float4*>(src + 4);
  bf16x8 v;
  v[0] = (bf16)f0.x; v[1] = (bf16)f0.y; v[2] = (bf16)f0.z; v[3] = (bf16)f0.w;
  v[4] = (bf16)f1.x; v[5] = (bf16)f1.y; v[6] = (bf16)f1.z; v[7] = (bf16)f1.w;
  *reinterpret_cast<bf16x8*>(dst + (size_t)row * rb + ((k8 * 2) ^ ((row & 7) << 4))) = v;
}

// A = activations (global), B = weights (LDS, XOR-swizzled), K=1024
template <int MT, int NT, bool SC>
__device__ __forceinline__ void mmA(const bf16* __restrict__ A, const char* __restrict__ ldsb,
                                    f32x4 (&acc)[MT][NT], const int m0, const int r,
                                    const int kq) {
#pragma unroll 8
  for (int k0 = 0; k0 < 1024; k0 += 32) {
    const int k = k0 + kq * 8;
    bf16x8 a[MT];
#pragma unroll
    for (int mi = 0; mi < MT; ++mi) {
      const bf16* p = A + (size_t)(m0 + mi * 16 + r) * 1024 + k;
      a[mi] = SC ? ldA_sc(p) : ldfrag(p);
    }
#pragma unroll
    for (int nt = 0; nt < NT; ++nt) {
      const bf16x8 b = *reinterpret_cast<const bf16x8*>(
          ldsb + (size_t)(nt * 16 + r) * 2048 + ((k * 2) ^ ((r & 7) << 4)));
#pragma unroll
      for (int mi = 0; mi < MT; ++mi) acc[mi][nt] = MFMA16(a[mi], b, acc[mi][nt]);
    }
  }
}

// A = activations (global), B = weights from GLOBAL bf16 (read-only, L2-cached)
template <int MT, int NT>
__device__ __forceinline__ void mmAW(const bf16* __restrict__ A, const bf16* __restrict__ W,
                                     f32x4 (&acc)[MT][NT], const int m0, const int r,
                                     const int kq) {
#pragma unroll 8
  for (int k0 = 0; k0 < 1024; k0 += 32) {
    const int k = k0 + kq * 8;
    bf16x8 a[MT];
#pragma unroll
    for (int mi = 0; mi < MT; ++mi)
      a[mi] = ldfrag(A + (size_t)(m0 + mi * 16 + r) * 1024 + k);
#pragma unroll
    for (int nt = 0; nt < NT; ++nt) {
      const bf16x8 b = ldfrag(W + (size_t)(nt * 16 + r) * 1024 + k);
#pragma unroll
      for (int mi = 0; mi < MT; ++mi) acc[mi][nt] = MFMA16(a[mi], b, acc[mi][nt]);
    }
  }
}

__global__ void __launch_bounds__(256, 1) k_gru(GP P) {
  extern __shared__ char lds[];
  const int w = blockIdx.x;
  const int tid = threadIdx.x;
  const int r16 = tid & 15, q = (tid >> 4) & 3, wv = tid >> 6;
  const size_t HB = 131072;
  const int grp = w >> 6;        // 0=L0a 1=L0b 2=L1a 3=L1b
  const int idx = w & 63;
  const int half = grp & 1;
  const int c0 = idx * 16;
  const int m0 = wv * 16;                   // local batch tile (M=64 per group)
  const size_t off = (size_t)half * 64 * 1024;  // half-batch offset (elems)
  float* hid = P.out + (size_t)128 * 512 * 1024;

  if (grp < 2) {
    // =================== L0 half-chain (self-contained) ===================
    for (int ch = tid; ch < 32 * 128; ch += 256) {  // z rows 0-15, r rows 16-31
      const int row = ch >> 7, k8 = (ch & 127) * 8;
      const int gate = row >> 4, col = c0 + (row & 15);
      stage_row8(lds, row, 2048, k8, P.Wh + ((size_t)(gate * 1024 + col)) * 1024 + k8);
    }
    for (int ch = tid; ch < 16 * 128; ch += 256) {  // g
      const int row = ch >> 7, k8 = (ch & 127) * 8;
      stage_row8(lds + 65536, row, 2048, k8,
                 P.Wh + ((size_t)(2 * 1024 + c0 + row)) * 1024 + k8);
    }
    __syncthreads();
    int* F = P.bar + grp * 64;
    const int gB = half * 64 + m0 + q * 4;  // global batch base of this thread's 4 rows
    float h0reg[4] = {}, z0[4];
    bf16x4 pz, pr, pg;
    pz = *reinterpret_cast<const bf16x4*>(P.gx0T + (size_t)(c0 + r16) * 128 + gB);
    pr = *reinterpret_cast<const bf16x4*>(P.gx0T + (size_t)(1024 + c0 + r16) * 128 + gB);
    for (int t = 0; t < 512; ++t) {
      if (t) {
        if (tid < 64) spin1(F + tid, 2 * t);
        __syncthreads();
      }
      pg = *reinterpret_cast<const bf16x4*>(
          P.gx0T + ((size_t)t * 3072 + 2048 + c0 + r16) * 128 + gB);
      f32x4 acc[1][2] = {};
      mmA<1, 2, false>(P.h0seq + (size_t)t * HB + off, lds, acc, m0, r16, q);
      bf16* rh0t = P.rh0 + (size_t)(P.sc_rh ? (t & 1) : t) * HB;
#pragma unroll
      for (int j = 0; j < 4; ++j) {
        z0[j] = sigmf(acc[0][0][j] + (float)pz[j]);
        const float rv = sigmf(acc[0][1][j] + (float)pr[j]);
        st2_llc(rh0t + (size_t)(gB + j) * 1024 + c0 + r16, (bf16)(rv * h0reg[j]));
      }
      publish(F + idx, 2 * t + 1);

      if (tid < 64) spin1(F + tid, 2 * t + 1);
      __syncthreads();
      if (t + 1 < 512) {
        const bf16* gxz = P.gx0T + ((size_t)(t + 1) * 3072 + c0 + r16) * 128 + gB;
        pz = *reinterpret_cast<const bf16x4*>(gxz);
        pr = *reinterpret_cast<const bf16x4*>(gxz + (size_t)1024 * 128);
      }
      f32x4 ac2[1][1] = {};
      if (P.sc_rh) mmA<1, 1, true>(rh0t + off, lds + 65536, ac2, m0, r16, q);
      else mmA<1, 1, false>(rh0t + off, lds + 65536, ac2, m0, r16, q);
      bf16* hsn = P.h0seq + (size_t)(t + 1) * HB;
#pragma unroll
      for (int j = 0; j < 4; ++j) {
        const float gv = tanhf(ac2[0][0][j] + (float)pg[j]);
        const float hn = z0[j] * h0reg[j] + (1.f - z0[j]) * gv;
        h0reg[j] = hn;
        st2_llc(hsn + (size_t)(gB + j) * 1024 + c0 + r16, (bf16)hn);
      }
      publish(F + idx, 2 * t + 2);
    }
#pragma unroll
    for (int j = 0; j < 4; ++j) hid[(size_t)(gB + j) * 2048 + c0 + r16] = h0reg[j];

  } else {
    // =================== L1 half-chain (+ OUT in slack) ===================
    // LDS: Wh1z @0 (32K), Wh1r @32768, Wh1g @65536, Why @98304 (each 16x2KB)
    for (int ch = tid; ch < 16 * 128; ch += 256) {
      const int row = ch >> 7, k8 = (ch & 127) * 8;
      stage_row8(lds, row, 2048, k8, P.Wh + ((size_t)(3 * 1024 + c0 + row)) * 1024 + k8);
      stage_row8(lds + 32768, row, 2048, k8,
                 P.Wh + ((size_t)(4 * 1024 + c0 + row)) * 1024 + k8);
      stage_row8(lds + 65536, row, 2048, k8,
                 P.Wh + ((size_t)(5 * 1024 + c0 + row)) * 1024 + k8);
      stage_row8(lds + 98304, row, 2048, k8, P.Why + ((size_t)(c0 + row)) * 1024 + k8);
    }
    __syncthreads();
    int* L0Fh = P.bar + half * 64;
    int* AF = P.bar + 128 + half * 128;
    int* BF = P.bar + 192 + half * 128;
    const bf16* Wxz = P.Wxb + (size_t)(3 * 1024 + c0) * 1024;
    const bf16* Wxr = P.Wxb + (size_t)(4 * 1024 + c0) * 1024;
    const bf16* Wxg = P.Wxb + (size_t)(5 * 1024 + c0) * 1024;
    const float bz = P.bh[3 * 1024 + c0 + r16];
    const float brv = P.bh[4 * 1024 + c0 + r16];
    const float bg = P.bh[5 * 1024 + c0 + r16];
    const float byv = P.by[c0 + r16];
    const int gB = half * 64 + m0 + q * 4;
    float h1reg[4] = {}, z1[4];
    for (int t = 0; t < 512; ++t) {
      // ---- phase A: z, r ----
      if (tid < 64) spin1(L0Fh + tid, 2 * (t + 1));
      else if (tid < 128) { if (t > 0) spin1(BF + (tid - 64), t); }
      __syncthreads();
      const bf16* h0p = P.h0seq + (size_t)(t + 1) * HB + off;
      const bf16* h1p = P.h1seq + (size_t)t * HB + off;
      f32x4 az[1][1] = {}, ar[1][1] = {};
      mmAW<1, 1>(h0p, Wxz, az, m0, r16, q);
      mmA<1, 1, false>(h1p, lds, az, m0, r16, q);
      mmAW<1, 1>(h0p, Wxr, ar, m0, r16, q);
      mmA<1, 1, false>(h1p, lds + 32768, ar, m0, r16, q);
      bf16* rh1t = P.rh1 + (size_t)(P.sc_rh ? (t & 1) : t) * HB;
#pragma unroll
      for (int j = 0; j < 4; ++j) {
        z1[j] = sigmf(az[0][0][j] + bz);
        const float rv = sigmf(ar[0][0][j] + brv);
        const float hp = (float)h1p[(size_t)(m0 + q * 4 + j) * 1024 + c0 + r16];
        st2_llc(rh1t + (size_t)(gB + j) * 1024 + c0 + r16, (bf16)(rv * hp));
      }
      publish(AF + idx, t + 1);

      // ---- phase B: g + update (+ OUT slack) ----
      if (tid < 64) spin1(AF + tid, t + 1);
      __syncthreads();
      f32x4 ag[1][1] = {};
      mmAW<1, 1>(h0p, Wxg, ag, m0, r16, q);
      if (P.sc_rh) mmA<1, 1, true>(rh1t + off, lds + 65536, ag, m0, r16, q);
      else mmA<1, 1, false>(rh1t + off, lds + 65536, ag, m0, r16, q);
      bf16* hsn = P.h1seq + (size_t)(t + 1) * HB;
#pragma unroll
      for (int j = 0; j < 4; ++j) {
        const float gv = tanhf(ag[0][0][j] + bg);
        const float hn = z1[j] * h1reg[j] + (1.f - z1[j]) * gv;
        h1reg[j] = hn;
        st2_llc(hsn + (size_t)(gB + j) * 1024 + c0 + r16, (bf16)hn);
      }
      publish(BF + idx, t + 1);

      if (t >= 4) {  // OUT: y[t-4] = h1seq[t-3] @ Why^T + by (zero wait)
        const int o = t - 4;
        f32x4 ao[1][1] = {};
        mmA<1, 1, false>(P.h1seq + (size_t)(o + 1) * HB + off, lds + 98304, ao, m0, r16, q);
#pragma unroll
        for (int j = 0; j < 4; ++j)
          P.out[((size_t)(gB + j) * 512 + o) * 1024 + c0 + r16] = ao[0][0][j] + byv;
      }
    }
    // tail OUTs o = 508..511
    if (tid < 64) spin1(BF + tid, 512);
    __syncthreads();
    for (int o = 508; o < 512; ++o) {
      f32x4 ao[1][1] = {};
      mmA<1, 1, false>(P.h1seq + (size_t)(o + 1) * HB + off, lds + 98304, ao, m0, r16, q);
#pragma unroll
      for (int j = 0; j < 4; ++j)
        P.out[((size_t)(gB + j) * 512 + o) * 1024 + c0 + r16] = ao[0][0][j] + byv;
    }
#pragma unroll
    for (int j = 0; j < 4; ++j)
      hid[(size_t)(gB + j) * 2048 + 1024 + c0 + r16] = h1reg[j];
  }
}

extern "C" void kernel_launch(void* const* d_in, const int* in_sizes, int n_in,
                              void* d_out, int out_size, void* d_ws, size_t ws_size,
                              hipStream_t stream) {
  const float* x = (const float*)d_in[0];
  const float* Wx = (const float*)d_in[1];
  const float* Wh = (const float*)d_in[2];
  const float* bh = (const float*)d_in[3];
  const float* Why = (const float*)d_in[4];
  const float* by = (const float*)d_in[5];
  float* out = (float*)d_out;

  const size_t HBb = (size_t)131072 * 2;
  auto al = [](size_t v) { return (v + 255) & ~(size_t)255; };
  const size_t szWxb = al((size_t)6291456 * 2);            // 12.6 MB
  const size_t szGx = al((size_t)512 * 3072 * 128 * 2);    // 384 MB
  const size_t szHseq = al((size_t)513 * HBb);             // 134.5 MB
  const size_t szRhFull = al((size_t)512 * HBb);
  const size_t szRhPar = al((size_t)2 * HBb);
  const size_t szBar = 4096;
  const size_t needFull = szWxb + szGx + 2 * szHseq + 2 * szRhFull + szBar;
  const int sc_rh = (ws_size >= needFull) ? 0 : 1;
  const size_t szRh = sc_rh ? szRhPar : szRhFull;

  char* ws = (char*)d_ws;
  size_t off = 0;
  auto alloc = [&](size_t bytes) -> void* {
    void* p = ws + off;
    off += bytes;
    return p;
  };
  bf16* Wxb = (bf16*)alloc(szWxb);
  bf16* gx0T = (bf16*)alloc(szGx);
  bf16* h0seq = (bf16*)alloc(szHseq);
  bf16* h1seq = (bf16*)alloc(szHseq);
  bf16* rh0 = (bf16*)alloc(szRh);
  bf16* rh1 = (bf16*)alloc(szRh);
  int* bar = (int*)alloc(szBar);

  hipFuncSetAttribute((const void*)k_gru, hipFuncAttributeMaxDynamicSharedMemorySize, 131072);

  k_cast4<<<1024, 256, 0, stream>>>(Wx, Wxb, 6291456 / 4);
  hipMemsetAsync(h0seq, 0, 262144, stream);  // h0seq[0] = 0
  hipMemsetAsync(h1seq, 0, 262144, stream);  // h1seq[0] = 0
  hipMemsetAsync(bar, 0, szBar, stream);

  k_gx0T<<<12288, 256, 0, stream>>>(x, Wxb, bh, gx0T);

  GP gp{Wh, bh, by, Why, Wxb, gx0T, h0seq, h1seq, rh0, rh1, out, bar, sc_rh};
  void* kargs[] = {&gp};
  hipLaunchCooperativeKernel((void*)k_gru, dim3(256), dim3(256), kargs, 131072, stream);
}